// Round 1
// baseline (632.459 us; speedup 1.0000x reference)
//
#include <hip/hip_runtime.h>
#include <math.h>

// ---------------------------------------------------------------------------
// GCN 3-layer: out = sigmoid( L3(relu(L2(relu(L1(x))))) @ Wl + bl )
// Each layer: hs = (x @ W) * dinv[row]   (matmul + scale epilogue)
//             z  = relu( dinv[d] * (sum_{s->d} hs[s] + hs[d]) + b )
// dinv[i] = rsqrt(1 + in_degree(i))  (self-loop included)
// CSR (by dst) built on device each launch via counting sort.
// ---------------------------------------------------------------------------

__global__ void k_count(const int* __restrict__ dst, int E, int* __restrict__ cnt) {
    int i = blockIdx.x * blockDim.x + threadIdx.x;
    if (i < E) atomicAdd(&cnt[dst[i]], 1);
}

__global__ void k_dinv(const int* __restrict__ cnt, float* __restrict__ dinv, int n) {
    int i = blockIdx.x * blockDim.x + threadIdx.x;
    if (i < n) dinv[i] = rsqrtf((float)(cnt[i] + 1));
}

// Block-level scan: each block handles 1024 elements (4/thread). Writes local
// exclusive scan into row_ptr and the block total into bsum[b].
__global__ __launch_bounds__(256) void k_scan1(const int* __restrict__ cnt,
                                               int* __restrict__ row_ptr,
                                               int* __restrict__ bsum, int n) {
    __shared__ int s[256];
    int b = blockIdx.x, tid = threadIdx.x;
    int base = b * 1024 + tid * 4;
    int v0 = (base + 0 < n) ? cnt[base + 0] : 0;
    int v1 = (base + 1 < n) ? cnt[base + 1] : 0;
    int v2 = (base + 2 < n) ? cnt[base + 2] : 0;
    int v3 = (base + 3 < n) ? cnt[base + 3] : 0;
    int tsum = v0 + v1 + v2 + v3;
    s[tid] = tsum;
    __syncthreads();
    for (int off = 1; off < 256; off <<= 1) {
        int t = (tid >= off) ? s[tid - off] : 0;
        __syncthreads();
        s[tid] += t;
        __syncthreads();
    }
    int texcl = s[tid] - tsum;  // exclusive prefix of this thread's group
    if (tid == 255) bsum[b] = s[255];
    if (base + 0 < n) row_ptr[base + 0] = texcl;
    if (base + 1 < n) row_ptr[base + 1] = texcl + v0;
    if (base + 2 < n) row_ptr[base + 2] = texcl + v0 + v1;
    if (base + 3 < n) row_ptr[base + 3] = texcl + v0 + v1 + v2;
}

// Exclusive scan of block sums (nb <= 128). Single block of 128 threads.
__global__ void k_scan2(int* __restrict__ bsum, int nb) {
    __shared__ int s[128];
    int tid = threadIdx.x;
    int v = (tid < nb) ? bsum[tid] : 0;
    s[tid] = v;
    __syncthreads();
    for (int off = 1; off < 128; off <<= 1) {
        int t = (tid >= off) ? s[tid - off] : 0;
        __syncthreads();
        s[tid] += t;
        __syncthreads();
    }
    if (tid < nb) bsum[tid] = s[tid] - v;  // exclusive
}

__global__ void k_scan3(int* __restrict__ row_ptr, const int* __restrict__ bsum,
                        int n, int E) {
    int i = blockIdx.x * blockDim.x + threadIdx.x;
    if (i < n) row_ptr[i] += bsum[i >> 10];
    else if (i == n) row_ptr[n] = E;  // total = all edges
}

__global__ void k_fill(const int* __restrict__ src, const int* __restrict__ dst, int E,
                       const int* __restrict__ row_ptr, int* __restrict__ fillc,
                       int* __restrict__ col) {
    int i = blockIdx.x * blockDim.x + threadIdx.x;
    if (i < E) {
        int d = dst[i];
        int pos = row_ptr[d] + atomicAdd(&fillc[d], 1);
        col[pos] = src[i];
    }
}

// hs[row] = (x[row] @ W) * dinv[row].  256 threads, per-thread 4 rows x 4 cols.
template <int IN, int OUT>
__global__ __launch_bounds__(256) void k_matmul_scale(const float* __restrict__ x,
                                                      const float* __restrict__ W,
                                                      const float* __restrict__ dinv,
                                                      float* __restrict__ out, int n) {
    constexpr int CG = OUT / 4;      // column groups (float4 per thread)
    constexpr int RG = 256 / CG;     // row groups
    constexpr int ROWS = RG * 4;     // rows per block
    __shared__ float xs[ROWS][IN];

    int tid = threadIdx.x;
    int rowbase = blockIdx.x * ROWS;

    // stage x tile (zero-fill rows beyond n)
    constexpr int TOT4 = ROWS * IN / 4;
    for (int i = tid; i < TOT4; i += 256) {
        int r = i / (IN / 4);
        int kk = i % (IN / 4);
        int row = rowbase + r;
        float4 v = make_float4(0.f, 0.f, 0.f, 0.f);
        if (row < n) v = ((const float4*)x)[(size_t)row * (IN / 4) + kk];
        ((float4*)&xs[r][0])[kk] = v;
    }
    __syncthreads();

    int tx = tid % CG;
    int ty = tid / CG;
    const float4* W4 = (const float4*)W;
    const float4* xr0 = (const float4*)&xs[ty * 4 + 0][0];
    const float4* xr1 = (const float4*)&xs[ty * 4 + 1][0];
    const float4* xr2 = (const float4*)&xs[ty * 4 + 2][0];
    const float4* xr3 = (const float4*)&xs[ty * 4 + 3][0];

    float4 acc0 = make_float4(0, 0, 0, 0), acc1 = acc0, acc2 = acc0, acc3 = acc0;

#pragma unroll 4
    for (int kk = 0; kk < IN / 4; ++kk) {
        float4 a0 = xr0[kk], a1 = xr1[kk], a2 = xr2[kk], a3 = xr3[kk];
        float a0a[4] = {a0.x, a0.y, a0.z, a0.w};
        float a1a[4] = {a1.x, a1.y, a1.z, a1.w};
        float a2a[4] = {a2.x, a2.y, a2.z, a2.w};
        float a3a[4] = {a3.x, a3.y, a3.z, a3.w};
#pragma unroll
        for (int j = 0; j < 4; ++j) {
            float4 w = W4[(kk * 4 + j) * CG + tx];
            acc0.x += a0a[j] * w.x; acc0.y += a0a[j] * w.y; acc0.z += a0a[j] * w.z; acc0.w += a0a[j] * w.w;
            acc1.x += a1a[j] * w.x; acc1.y += a1a[j] * w.y; acc1.z += a1a[j] * w.z; acc1.w += a1a[j] * w.w;
            acc2.x += a2a[j] * w.x; acc2.y += a2a[j] * w.y; acc2.z += a2a[j] * w.z; acc2.w += a2a[j] * w.w;
            acc3.x += a3a[j] * w.x; acc3.y += a3a[j] * w.y; acc3.z += a3a[j] * w.z; acc3.w += a3a[j] * w.w;
        }
    }

    int row0 = rowbase + ty * 4;
    float4* out4 = (float4*)out;
#pragma unroll
    for (int r = 0; r < 4; ++r) {
        int row = row0 + r;
        if (row < n) {
            float dsc = dinv[row];
            float4 a = (r == 0) ? acc0 : (r == 1) ? acc1 : (r == 2) ? acc2 : acc3;
            float4 o = make_float4(a.x * dsc, a.y * dsc, a.z * dsc, a.w * dsc);
            out4[(size_t)row * CG + tx] = o;
        }
    }
}

// out[d][f] = act( dinv[d] * (hs[d][f] + sum_{j} hs[col[j]][f]) + b[f] )
template <int F, bool RELU>
__global__ __launch_bounds__(256) void k_aggregate(const float* __restrict__ hs,
                                                   const float* __restrict__ dinv,
                                                   const float* __restrict__ bias,
                                                   const int* __restrict__ row_ptr,
                                                   const int* __restrict__ col,
                                                   float* __restrict__ out, int n) {
    int t = blockIdx.x * 256 + threadIdx.x;
    int node = t / F;
    int f = t % F;
    if (node >= n) return;
    float acc = hs[(size_t)node * F + f];  // self loop (hs already *dinv[node])
    int beg = row_ptr[node], end = row_ptr[node + 1];
    int j = beg;
    for (; j + 3 < end; j += 4) {
        int s0 = col[j], s1 = col[j + 1], s2 = col[j + 2], s3 = col[j + 3];
        float v0 = hs[(size_t)s0 * F + f];
        float v1 = hs[(size_t)s1 * F + f];
        float v2 = hs[(size_t)s2 * F + f];
        float v3 = hs[(size_t)s3 * F + f];
        acc += v0; acc += v1; acc += v2; acc += v3;
    }
    for (; j < end; ++j) acc += hs[(size_t)col[j] * F + f];
    float v = fmaf(acc, dinv[node], bias[f]);
    out[(size_t)node * F + f] = RELU ? fmaxf(v, 0.f) : v;
}

__global__ void k_final(const float* __restrict__ z, const float* __restrict__ Wl,
                        const float* __restrict__ bl, float* __restrict__ out, int n) {
    int i = blockIdx.x * blockDim.x + threadIdx.x;
    if (i >= n) return;
    float acc = bl[0];
#pragma unroll
    for (int k = 0; k < 32; ++k) acc += z[(size_t)i * 32 + k] * Wl[k];
    out[i] = 1.f / (1.f + expf(-acc));
}

extern "C" void kernel_launch(void* const* d_in, const int* in_sizes, int n_in,
                              void* d_out, int out_size, void* d_ws, size_t ws_size,
                              hipStream_t stream) {
    const float* x  = (const float*)d_in[0];
    const int*   ei = (const int*)d_in[1];
    const float* W1 = (const float*)d_in[2];
    const float* b1 = (const float*)d_in[3];
    const float* W2 = (const float*)d_in[4];
    const float* b2 = (const float*)d_in[5];
    const float* W3 = (const float*)d_in[6];
    const float* b3 = (const float*)d_in[7];
    const float* Wl = (const float*)d_in[8];
    const float* bl = (const float*)d_in[9];

    const int N = in_sizes[0] / 128;
    const int E = in_sizes[1] / 2;
    const int* src = ei;
    const int* dst = ei + E;

    char* ws = (char*)d_ws;
    size_t off = 0;
    auto take = [&](size_t bytes) -> char* {
        char* p = ws + off;
        off += (bytes + 255) & ~(size_t)255;
        return p;
    };
    int*   cnt     = (int*)take((size_t)N * 4);
    int*   fillc   = (int*)take((size_t)N * 4);
    int*   row_ptr = (int*)take((size_t)(N + 1) * 4);
    int*   bsum    = (int*)take(1024 * 4);
    int*   col     = (int*)take((size_t)E * 4);
    float* dinv    = (float*)take((size_t)N * 4);
    float* bufA    = (float*)take((size_t)N * 128 * 4);
    float* bufB    = (float*)take((size_t)N * 128 * 4);
    (void)ws_size;

    hipMemsetAsync(cnt, 0, (size_t)N * 4, stream);
    hipMemsetAsync(fillc, 0, (size_t)N * 4, stream);

    int gE = (E + 255) / 256;
    int gN = (N + 255) / 256;
    int nb = (N + 1023) / 1024;

    // ---- CSR build ----
    k_count<<<gE, 256, 0, stream>>>(dst, E, cnt);
    k_dinv<<<gN, 256, 0, stream>>>(cnt, dinv, N);
    k_scan1<<<nb, 256, 0, stream>>>(cnt, row_ptr, bsum, N);
    k_scan2<<<1, 128, 0, stream>>>(bsum, nb);
    k_scan3<<<(N + 1 + 255) / 256, 256, 0, stream>>>(row_ptr, bsum, N, E);
    k_fill<<<gE, 256, 0, stream>>>(src, dst, E, row_ptr, fillc, col);

    // ---- Layer 1: 128 -> 128 ----
    k_matmul_scale<128, 128><<<(N + 31) / 32, 256, 0, stream>>>(x, W1, dinv, bufA, N);
    k_aggregate<128, true><<<((size_t)N * 128 + 255) / 256, 256, 0, stream>>>(
        bufA, dinv, b1, row_ptr, col, bufB, N);

    // ---- Layer 2: 128 -> 64 ----
    k_matmul_scale<128, 64><<<(N + 63) / 64, 256, 0, stream>>>(bufB, W2, dinv, bufA, N);
    k_aggregate<64, true><<<((size_t)N * 64 + 255) / 256, 256, 0, stream>>>(
        bufA, dinv, b2, row_ptr, col, bufB, N);

    // ---- Layer 3: 64 -> 32 ----
    k_matmul_scale<64, 32><<<(N + 127) / 128, 256, 0, stream>>>(bufB, W3, dinv, bufA, N);
    k_aggregate<32, true><<<((size_t)N * 32 + 255) / 256, 256, 0, stream>>>(
        bufA, dinv, b3, row_ptr, col, bufB, N);

    // ---- Link head: [N,32] @ [32,1] + sigmoid ----
    k_final<<<gN, 256, 0, stream>>>(bufB, Wl, bl, (float*)d_out, N);
}

// Round 2
// 594.314 us; speedup vs baseline: 1.0642x; 1.0642x over previous
//
#include <hip/hip_runtime.h>
#include <math.h>

// ---------------------------------------------------------------------------
// GCN 3-layer: out = sigmoid( L3(relu(L2(relu(L1(x))))) @ Wl + bl )
// Each layer: hs = (x @ W) * dinv[row]   (matmul + scale epilogue)
//             z  = relu( dinv[d] * (sum_{s->d} hs[s] + hs[d]) + b )
// dinv[i] = rsqrt(1 + in_degree(i))  (self-loop included)
// CSR (by dst) built on device each launch via counting sort.
// R2: aggregate vectorized to float4/thread (latency-bound fix).
// ---------------------------------------------------------------------------

__global__ void k_count(const int* __restrict__ dst, int E, int* __restrict__ cnt) {
    int i = blockIdx.x * blockDim.x + threadIdx.x;
    if (i < E) atomicAdd(&cnt[dst[i]], 1);
}

__global__ void k_dinv(const int* __restrict__ cnt, float* __restrict__ dinv, int n) {
    int i = blockIdx.x * blockDim.x + threadIdx.x;
    if (i < n) dinv[i] = rsqrtf((float)(cnt[i] + 1));
}

// Block-level scan: each block handles 1024 elements (4/thread).
__global__ __launch_bounds__(256) void k_scan1(const int* __restrict__ cnt,
                                               int* __restrict__ row_ptr,
                                               int* __restrict__ bsum, int n) {
    __shared__ int s[256];
    int b = blockIdx.x, tid = threadIdx.x;
    int base = b * 1024 + tid * 4;
    int v0 = (base + 0 < n) ? cnt[base + 0] : 0;
    int v1 = (base + 1 < n) ? cnt[base + 1] : 0;
    int v2 = (base + 2 < n) ? cnt[base + 2] : 0;
    int v3 = (base + 3 < n) ? cnt[base + 3] : 0;
    int tsum = v0 + v1 + v2 + v3;
    s[tid] = tsum;
    __syncthreads();
    for (int off = 1; off < 256; off <<= 1) {
        int t = (tid >= off) ? s[tid - off] : 0;
        __syncthreads();
        s[tid] += t;
        __syncthreads();
    }
    int texcl = s[tid] - tsum;
    if (tid == 255) bsum[b] = s[255];
    if (base + 0 < n) row_ptr[base + 0] = texcl;
    if (base + 1 < n) row_ptr[base + 1] = texcl + v0;
    if (base + 2 < n) row_ptr[base + 2] = texcl + v0 + v1;
    if (base + 3 < n) row_ptr[base + 3] = texcl + v0 + v1 + v2;
}

__global__ void k_scan2(int* __restrict__ bsum, int nb) {
    __shared__ int s[128];
    int tid = threadIdx.x;
    int v = (tid < nb) ? bsum[tid] : 0;
    s[tid] = v;
    __syncthreads();
    for (int off = 1; off < 128; off <<= 1) {
        int t = (tid >= off) ? s[tid - off] : 0;
        __syncthreads();
        s[tid] += t;
        __syncthreads();
    }
    if (tid < nb) bsum[tid] = s[tid] - v;
}

__global__ void k_scan3(int* __restrict__ row_ptr, const int* __restrict__ bsum,
                        int n, int E) {
    int i = blockIdx.x * blockDim.x + threadIdx.x;
    if (i < n) row_ptr[i] += bsum[i >> 10];
    else if (i == n) row_ptr[n] = E;
}

__global__ void k_fill(const int* __restrict__ src, const int* __restrict__ dst, int E,
                       const int* __restrict__ row_ptr, int* __restrict__ fillc,
                       int* __restrict__ col) {
    int i = blockIdx.x * blockDim.x + threadIdx.x;
    if (i < E) {
        int d = dst[i];
        int pos = row_ptr[d] + atomicAdd(&fillc[d], 1);
        col[pos] = src[i];
    }
}

// hs[row] = (x[row] @ W) * dinv[row].  256 threads, per-thread 4 rows x 4 cols.
template <int IN, int OUT>
__global__ __launch_bounds__(256) void k_matmul_scale(const float* __restrict__ x,
                                                      const float* __restrict__ W,
                                                      const float* __restrict__ dinv,
                                                      float* __restrict__ out, int n) {
    constexpr int CG = OUT / 4;
    constexpr int RG = 256 / CG;
    constexpr int ROWS = RG * 4;
    __shared__ float xs[ROWS][IN];

    int tid = threadIdx.x;
    int rowbase = blockIdx.x * ROWS;

    constexpr int TOT4 = ROWS * IN / 4;
    for (int i = tid; i < TOT4; i += 256) {
        int r = i / (IN / 4);
        int kk = i % (IN / 4);
        int row = rowbase + r;
        float4 v = make_float4(0.f, 0.f, 0.f, 0.f);
        if (row < n) v = ((const float4*)x)[(size_t)row * (IN / 4) + kk];
        ((float4*)&xs[r][0])[kk] = v;
    }
    __syncthreads();

    int tx = tid % CG;
    int ty = tid / CG;
    const float4* W4 = (const float4*)W;
    const float4* xr0 = (const float4*)&xs[ty * 4 + 0][0];
    const float4* xr1 = (const float4*)&xs[ty * 4 + 1][0];
    const float4* xr2 = (const float4*)&xs[ty * 4 + 2][0];
    const float4* xr3 = (const float4*)&xs[ty * 4 + 3][0];

    float4 acc0 = make_float4(0, 0, 0, 0), acc1 = acc0, acc2 = acc0, acc3 = acc0;

#pragma unroll 4
    for (int kk = 0; kk < IN / 4; ++kk) {
        float4 a0 = xr0[kk], a1 = xr1[kk], a2 = xr2[kk], a3 = xr3[kk];
        float a0a[4] = {a0.x, a0.y, a0.z, a0.w};
        float a1a[4] = {a1.x, a1.y, a1.z, a1.w};
        float a2a[4] = {a2.x, a2.y, a2.z, a2.w};
        float a3a[4] = {a3.x, a3.y, a3.z, a3.w};
#pragma unroll
        for (int j = 0; j < 4; ++j) {
            float4 w = W4[(kk * 4 + j) * CG + tx];
            acc0.x += a0a[j] * w.x; acc0.y += a0a[j] * w.y; acc0.z += a0a[j] * w.z; acc0.w += a0a[j] * w.w;
            acc1.x += a1a[j] * w.x; acc1.y += a1a[j] * w.y; acc1.z += a1a[j] * w.z; acc1.w += a1a[j] * w.w;
            acc2.x += a2a[j] * w.x; acc2.y += a2a[j] * w.y; acc2.z += a2a[j] * w.z; acc2.w += a2a[j] * w.w;
            acc3.x += a3a[j] * w.x; acc3.y += a3a[j] * w.y; acc3.z += a3a[j] * w.z; acc3.w += a3a[j] * w.w;
        }
    }

    int row0 = rowbase + ty * 4;
    float4* out4 = (float4*)out;
#pragma unroll
    for (int r = 0; r < 4; ++r) {
        int row = row0 + r;
        if (row < n) {
            float dsc = dinv[row];
            float4 a = (r == 0) ? acc0 : (r == 1) ? acc1 : (r == 2) ? acc2 : acc3;
            float4 o = make_float4(a.x * dsc, a.y * dsc, a.z * dsc, a.w * dsc);
            out4[(size_t)row * CG + tx] = o;
        }
    }
}

// out[d][f4] = act( dinv[d] * (hs[d][f4] + sum_j hs[col[j]][f4]) + b[f4] )
// One thread per float4 of features; 4-way unrolled neighbor loop (64B in
// flight per thread) to hide L2/L3 gather latency.
template <int F, bool RELU>
__global__ __launch_bounds__(256) void k_aggregate_v4(const float* __restrict__ hs,
                                                      const float* __restrict__ dinv,
                                                      const float* __restrict__ bias,
                                                      const int* __restrict__ row_ptr,
                                                      const int* __restrict__ col,
                                                      float* __restrict__ out, int n) {
    constexpr int LPN = F / 4;  // lanes (threads) per node
    int t = blockIdx.x * 256 + threadIdx.x;
    int node = t / LPN;
    int fg = t % LPN;
    if (node >= n) return;

    const float4* h4 = (const float4*)hs;
    float4 acc = h4[(size_t)node * LPN + fg];  // self loop (already *dinv[node])
    int beg = row_ptr[node], end = row_ptr[node + 1];
    int j = beg;
    for (; j + 3 < end; j += 4) {
        int s0 = col[j], s1 = col[j + 1], s2 = col[j + 2], s3 = col[j + 3];
        float4 v0 = h4[(size_t)s0 * LPN + fg];
        float4 v1 = h4[(size_t)s1 * LPN + fg];
        float4 v2 = h4[(size_t)s2 * LPN + fg];
        float4 v3 = h4[(size_t)s3 * LPN + fg];
        acc.x += v0.x + v1.x + v2.x + v3.x;
        acc.y += v0.y + v1.y + v2.y + v3.y;
        acc.z += v0.z + v1.z + v2.z + v3.z;
        acc.w += v0.w + v1.w + v2.w + v3.w;
    }
    for (; j < end; ++j) {
        float4 v = h4[(size_t)col[j] * LPN + fg];
        acc.x += v.x; acc.y += v.y; acc.z += v.z; acc.w += v.w;
    }
    float dsc = dinv[node];
    float4 b = ((const float4*)bias)[fg];
    float4 o;
    o.x = fmaf(acc.x, dsc, b.x);
    o.y = fmaf(acc.y, dsc, b.y);
    o.z = fmaf(acc.z, dsc, b.z);
    o.w = fmaf(acc.w, dsc, b.w);
    if (RELU) {
        o.x = fmaxf(o.x, 0.f); o.y = fmaxf(o.y, 0.f);
        o.z = fmaxf(o.z, 0.f); o.w = fmaxf(o.w, 0.f);
    }
    ((float4*)out)[(size_t)node * LPN + fg] = o;
}

__global__ void k_final(const float* __restrict__ z, const float* __restrict__ Wl,
                        const float* __restrict__ bl, float* __restrict__ out, int n) {
    int i = blockIdx.x * blockDim.x + threadIdx.x;
    if (i >= n) return;
    const float4* z4 = (const float4*)(z + (size_t)i * 32);
    const float4* w4 = (const float4*)Wl;
    float acc = bl[0];
#pragma unroll
    for (int k = 0; k < 8; ++k) {
        float4 a = z4[k], w = w4[k];
        acc += a.x * w.x + a.y * w.y + a.z * w.z + a.w * w.w;
    }
    out[i] = 1.f / (1.f + expf(-acc));
}

extern "C" void kernel_launch(void* const* d_in, const int* in_sizes, int n_in,
                              void* d_out, int out_size, void* d_ws, size_t ws_size,
                              hipStream_t stream) {
    const float* x  = (const float*)d_in[0];
    const int*   ei = (const int*)d_in[1];
    const float* W1 = (const float*)d_in[2];
    const float* b1 = (const float*)d_in[3];
    const float* W2 = (const float*)d_in[4];
    const float* b2 = (const float*)d_in[5];
    const float* W3 = (const float*)d_in[6];
    const float* b3 = (const float*)d_in[7];
    const float* Wl = (const float*)d_in[8];
    const float* bl = (const float*)d_in[9];

    const int N = in_sizes[0] / 128;
    const int E = in_sizes[1] / 2;
    const int* src = ei;
    const int* dst = ei + E;

    char* ws = (char*)d_ws;
    size_t off = 0;
    auto take = [&](size_t bytes) -> char* {
        char* p = ws + off;
        off += (bytes + 255) & ~(size_t)255;
        return p;
    };
    int*   cnt     = (int*)take((size_t)N * 4);
    int*   fillc   = (int*)take((size_t)N * 4);
    int*   row_ptr = (int*)take((size_t)(N + 1) * 4);
    int*   bsum    = (int*)take(1024 * 4);
    int*   col     = (int*)take((size_t)E * 4);
    float* dinv    = (float*)take((size_t)N * 4);
    float* bufA    = (float*)take((size_t)N * 128 * 4);
    float* bufB    = (float*)take((size_t)N * 128 * 4);
    (void)ws_size;

    hipMemsetAsync(cnt, 0, (size_t)N * 4, stream);
    hipMemsetAsync(fillc, 0, (size_t)N * 4, stream);

    int gE = (E + 255) / 256;
    int gN = (N + 255) / 256;
    int nb = (N + 1023) / 1024;

    // ---- CSR build ----
    k_count<<<gE, 256, 0, stream>>>(dst, E, cnt);
    k_dinv<<<gN, 256, 0, stream>>>(cnt, dinv, N);
    k_scan1<<<nb, 256, 0, stream>>>(cnt, row_ptr, bsum, N);
    k_scan2<<<1, 128, 0, stream>>>(bsum, nb);
    k_scan3<<<(N + 1 + 255) / 256, 256, 0, stream>>>(row_ptr, bsum, N, E);
    k_fill<<<gE, 256, 0, stream>>>(src, dst, E, row_ptr, fillc, col);

    // ---- Layer 1: 128 -> 128 ----
    k_matmul_scale<128, 128><<<(N + 31) / 32, 256, 0, stream>>>(x, W1, dinv, bufA, N);
    k_aggregate_v4<128, true><<<((size_t)N * 32 + 255) / 256, 256, 0, stream>>>(
        bufA, dinv, b1, row_ptr, col, bufB, N);

    // ---- Layer 2: 128 -> 64 ----
    k_matmul_scale<128, 64><<<(N + 63) / 64, 256, 0, stream>>>(bufB, W2, dinv, bufA, N);
    k_aggregate_v4<64, true><<<((size_t)N * 16 + 255) / 256, 256, 0, stream>>>(
        bufA, dinv, b2, row_ptr, col, bufB, N);

    // ---- Layer 3: 64 -> 32 ----
    k_matmul_scale<64, 32><<<(N + 127) / 128, 256, 0, stream>>>(bufB, W3, dinv, bufA, N);
    k_aggregate_v4<32, true><<<((size_t)N * 8 + 255) / 256, 256, 0, stream>>>(
        bufA, dinv, b3, row_ptr, col, bufB, N);

    // ---- Link head: [N,32] @ [32,1] + sigmoid ----
    k_final<<<gN, 256, 0, stream>>>(bufB, Wl, bl, (float*)d_out, N);
}

// Round 3
// 505.903 us; speedup vs baseline: 1.2502x; 1.1748x over previous
//
#include <hip/hip_runtime.h>
#include <hip/hip_fp16.h>
#include <math.h>

// ---------------------------------------------------------------------------
// GCN 3-layer: out = sigmoid( L3(relu(L2(relu(L1(x))))) @ Wl + bl )
// Each layer: hs = (x @ W) * dinv[row]   (matmul + scale epilogue, fp16 out)
//             z  = relu( dinv[d] * (hs[d] + sum_{s->d} hs[s]) + b )  (fp16 out)
// All accumulation fp32; intermediates stored fp16 to halve the gather
// traffic on the L2-miss path (the R2 bottleneck: ~3.7 TB/s fetch ceiling).
// ---------------------------------------------------------------------------

union H8 { float4 f4; __half2 h2[4]; };
union H4 { float2 f2; __half2 h2[2]; };

__global__ void k_count(const int* __restrict__ dst, int E, int* __restrict__ cnt) {
    int i = blockIdx.x * blockDim.x + threadIdx.x;
    if (i < E) atomicAdd(&cnt[dst[i]], 1);
}

__global__ void k_dinv(const int* __restrict__ cnt, float* __restrict__ dinv, int n) {
    int i = blockIdx.x * blockDim.x + threadIdx.x;
    if (i < n) dinv[i] = rsqrtf((float)(cnt[i] + 1));
}

__global__ __launch_bounds__(256) void k_scan1(const int* __restrict__ cnt,
                                               int* __restrict__ row_ptr,
                                               int* __restrict__ bsum, int n) {
    __shared__ int s[256];
    int b = blockIdx.x, tid = threadIdx.x;
    int base = b * 1024 + tid * 4;
    int v0 = (base + 0 < n) ? cnt[base + 0] : 0;
    int v1 = (base + 1 < n) ? cnt[base + 1] : 0;
    int v2 = (base + 2 < n) ? cnt[base + 2] : 0;
    int v3 = (base + 3 < n) ? cnt[base + 3] : 0;
    int tsum = v0 + v1 + v2 + v3;
    s[tid] = tsum;
    __syncthreads();
    for (int off = 1; off < 256; off <<= 1) {
        int t = (tid >= off) ? s[tid - off] : 0;
        __syncthreads();
        s[tid] += t;
        __syncthreads();
    }
    int texcl = s[tid] - tsum;
    if (tid == 255) bsum[b] = s[255];
    if (base + 0 < n) row_ptr[base + 0] = texcl;
    if (base + 1 < n) row_ptr[base + 1] = texcl + v0;
    if (base + 2 < n) row_ptr[base + 2] = texcl + v0 + v1;
    if (base + 3 < n) row_ptr[base + 3] = texcl + v0 + v1 + v2;
}

__global__ void k_scan2(int* __restrict__ bsum, int nb) {
    __shared__ int s[128];
    int tid = threadIdx.x;
    int v = (tid < nb) ? bsum[tid] : 0;
    s[tid] = v;
    __syncthreads();
    for (int off = 1; off < 128; off <<= 1) {
        int t = (tid >= off) ? s[tid - off] : 0;
        __syncthreads();
        s[tid] += t;
        __syncthreads();
    }
    if (tid < nb) bsum[tid] = s[tid] - v;
}

__global__ void k_scan3(int* __restrict__ row_ptr, const int* __restrict__ bsum,
                        int n, int E) {
    int i = blockIdx.x * blockDim.x + threadIdx.x;
    if (i < n) row_ptr[i] += bsum[i >> 10];
    else if (i == n) row_ptr[n] = E;
}

__global__ void k_fill(const int* __restrict__ src, const int* __restrict__ dst, int E,
                       const int* __restrict__ row_ptr, int* __restrict__ fillc,
                       int* __restrict__ col) {
    int i = blockIdx.x * blockDim.x + threadIdx.x;
    if (i < E) {
        int d = dst[i];
        int pos = row_ptr[d] + atomicAdd(&fillc[d], 1);
        col[pos] = src[i];
    }
}

// hs[row] = half( (x[row] @ W) * dinv[row] ).  x is fp32 (XHALF=false) or
// fp16 (XHALF=true); LDS tile holds fp32 either way.
template <int IN, int OUT, bool XHALF>
__global__ __launch_bounds__(256) void k_matmul_scale(const void* __restrict__ xv,
                                                      const float* __restrict__ W,
                                                      const float* __restrict__ dinv,
                                                      __half* __restrict__ out, int n) {
    constexpr int CG = OUT / 4;      // threads per row (4 cols each)
    constexpr int RG = 256 / CG;
    constexpr int ROWS = RG * 4;
    __shared__ float xs[ROWS][IN];

    int tid = threadIdx.x;
    int rowbase = blockIdx.x * ROWS;

    if (!XHALF) {
        constexpr int TOT4 = ROWS * IN / 4;
        const float4* x4 = (const float4*)xv;
        for (int i = tid; i < TOT4; i += 256) {
            int r = i / (IN / 4);
            int kk = i % (IN / 4);
            int row = rowbase + r;
            float4 v = make_float4(0.f, 0.f, 0.f, 0.f);
            if (row < n) v = x4[(size_t)row * (IN / 4) + kk];
            ((float4*)&xs[r][0])[kk] = v;
        }
    } else {
        constexpr int TOT8 = ROWS * IN / 8;
        const float4* x4 = (const float4*)xv;  // 8 halves per float4
        for (int i = tid; i < TOT8; i += 256) {
            int r = i / (IN / 8);
            int kk = i % (IN / 8);
            int row = rowbase + r;
            H8 u;
            u.f4 = make_float4(0.f, 0.f, 0.f, 0.f);
            if (row < n) u.f4 = x4[(size_t)row * (IN / 8) + kk];
#pragma unroll
            for (int q = 0; q < 4; ++q) {
                float2 f = __half22float2(u.h2[q]);
                xs[r][kk * 8 + 2 * q + 0] = f.x;
                xs[r][kk * 8 + 2 * q + 1] = f.y;
            }
        }
    }
    __syncthreads();

    int tx = tid % CG;
    int ty = tid / CG;
    const float4* W4 = (const float4*)W;
    const float4* xr0 = (const float4*)&xs[ty * 4 + 0][0];
    const float4* xr1 = (const float4*)&xs[ty * 4 + 1][0];
    const float4* xr2 = (const float4*)&xs[ty * 4 + 2][0];
    const float4* xr3 = (const float4*)&xs[ty * 4 + 3][0];

    float4 acc0 = make_float4(0, 0, 0, 0), acc1 = acc0, acc2 = acc0, acc3 = acc0;

#pragma unroll 4
    for (int kk = 0; kk < IN / 4; ++kk) {
        float4 a0 = xr0[kk], a1 = xr1[kk], a2 = xr2[kk], a3 = xr3[kk];
        float a0a[4] = {a0.x, a0.y, a0.z, a0.w};
        float a1a[4] = {a1.x, a1.y, a1.z, a1.w};
        float a2a[4] = {a2.x, a2.y, a2.z, a2.w};
        float a3a[4] = {a3.x, a3.y, a3.z, a3.w};
#pragma unroll
        for (int j = 0; j < 4; ++j) {
            float4 w = W4[(kk * 4 + j) * CG + tx];
            acc0.x += a0a[j] * w.x; acc0.y += a0a[j] * w.y; acc0.z += a0a[j] * w.z; acc0.w += a0a[j] * w.w;
            acc1.x += a1a[j] * w.x; acc1.y += a1a[j] * w.y; acc1.z += a1a[j] * w.z; acc1.w += a1a[j] * w.w;
            acc2.x += a2a[j] * w.x; acc2.y += a2a[j] * w.y; acc2.z += a2a[j] * w.z; acc2.w += a2a[j] * w.w;
            acc3.x += a3a[j] * w.x; acc3.y += a3a[j] * w.y; acc3.z += a3a[j] * w.z; acc3.w += a3a[j] * w.w;
        }
    }

    int row0 = rowbase + ty * 4;
    float2* out2 = (float2*)out;  // 4 halves per float2
#pragma unroll
    for (int r = 0; r < 4; ++r) {
        int row = row0 + r;
        if (row < n) {
            float dsc = dinv[row];
            float4 a = (r == 0) ? acc0 : (r == 1) ? acc1 : (r == 2) ? acc2 : acc3;
            H4 u;
            u.h2[0] = __floats2half2_rn(a.x * dsc, a.y * dsc);
            u.h2[1] = __floats2half2_rn(a.z * dsc, a.w * dsc);
            out2[(size_t)row * CG + tx] = u.f2;
        }
    }
}

// out[d][f8] = act( dinv[d]*(hs[d][f8] + sum_j hs[col[j]][f8]) + b[f8] )
// fp16 storage, fp32 accumulate. 8 features/thread => 16B loads.
template <int F, bool RELU>
__global__ __launch_bounds__(256) void k_aggregate_h(const __half* __restrict__ hs,
                                                     const float* __restrict__ dinv,
                                                     const float* __restrict__ bias,
                                                     const int* __restrict__ row_ptr,
                                                     const int* __restrict__ col,
                                                     __half* __restrict__ out, int n) {
    constexpr int LPN = F / 8;  // threads per node
    int t = blockIdx.x * 256 + threadIdx.x;
    int node = t / LPN;
    int fg = t % LPN;
    if (node >= n) return;

    const float4* h4 = (const float4*)hs;  // 8 halves each
    float acc[8];
    {
        H8 u;
        u.f4 = h4[(size_t)node * LPN + fg];  // self loop
#pragma unroll
        for (int q = 0; q < 4; ++q) {
            float2 f = __half22float2(u.h2[q]);
            acc[2 * q + 0] = f.x;
            acc[2 * q + 1] = f.y;
        }
    }
    int beg = row_ptr[node], end = row_ptr[node + 1];
    int j = beg;
    for (; j + 3 < end; j += 4) {
        int s0 = col[j], s1 = col[j + 1], s2 = col[j + 2], s3 = col[j + 3];
        H8 u0, u1, u2, u3;
        u0.f4 = h4[(size_t)s0 * LPN + fg];
        u1.f4 = h4[(size_t)s1 * LPN + fg];
        u2.f4 = h4[(size_t)s2 * LPN + fg];
        u3.f4 = h4[(size_t)s3 * LPN + fg];
#pragma unroll
        for (int q = 0; q < 4; ++q) {
            float2 f0 = __half22float2(u0.h2[q]);
            float2 f1 = __half22float2(u1.h2[q]);
            float2 f2 = __half22float2(u2.h2[q]);
            float2 f3 = __half22float2(u3.h2[q]);
            acc[2 * q + 0] += (f0.x + f1.x) + (f2.x + f3.x);
            acc[2 * q + 1] += (f0.y + f1.y) + (f2.y + f3.y);
        }
    }
    for (; j < end; ++j) {
        H8 u;
        u.f4 = h4[(size_t)col[j] * LPN + fg];
#pragma unroll
        for (int q = 0; q < 4; ++q) {
            float2 f = __half22float2(u.h2[q]);
            acc[2 * q + 0] += f.x;
            acc[2 * q + 1] += f.y;
        }
    }
    float dsc = dinv[node];
    H8 o;
#pragma unroll
    for (int q = 0; q < 4; ++q) {
        float v0 = fmaf(acc[2 * q + 0], dsc, bias[fg * 8 + 2 * q + 0]);
        float v1 = fmaf(acc[2 * q + 1], dsc, bias[fg * 8 + 2 * q + 1]);
        if (RELU) { v0 = fmaxf(v0, 0.f); v1 = fmaxf(v1, 0.f); }
        o.h2[q] = __floats2half2_rn(v0, v1);
    }
    ((float4*)out)[(size_t)node * LPN + fg] = o.f4;
}

__global__ void k_final(const __half* __restrict__ z, const float* __restrict__ Wl,
                        const float* __restrict__ bl, float* __restrict__ out, int n) {
    int i = blockIdx.x * blockDim.x + threadIdx.x;
    if (i >= n) return;
    const float4* z4 = (const float4*)(z + (size_t)i * 32);  // 4 x 8 halves
    float acc = bl[0];
#pragma unroll
    for (int k = 0; k < 4; ++k) {
        H8 u;
        u.f4 = z4[k];
#pragma unroll
        for (int q = 0; q < 4; ++q) {
            float2 f = __half22float2(u.h2[q]);
            acc += f.x * Wl[k * 8 + 2 * q + 0] + f.y * Wl[k * 8 + 2 * q + 1];
        }
    }
    out[i] = 1.f / (1.f + expf(-acc));
}

extern "C" void kernel_launch(void* const* d_in, const int* in_sizes, int n_in,
                              void* d_out, int out_size, void* d_ws, size_t ws_size,
                              hipStream_t stream) {
    const float* x  = (const float*)d_in[0];
    const int*   ei = (const int*)d_in[1];
    const float* W1 = (const float*)d_in[2];
    const float* b1 = (const float*)d_in[3];
    const float* W2 = (const float*)d_in[4];
    const float* b2 = (const float*)d_in[5];
    const float* W3 = (const float*)d_in[6];
    const float* b3 = (const float*)d_in[7];
    const float* Wl = (const float*)d_in[8];
    const float* bl = (const float*)d_in[9];

    const int N = in_sizes[0] / 128;
    const int E = in_sizes[1] / 2;
    const int* src = ei;
    const int* dst = ei + E;

    char* ws = (char*)d_ws;
    size_t off = 0;
    auto take = [&](size_t bytes) -> char* {
        char* p = ws + off;
        off += (bytes + 255) & ~(size_t)255;
        return p;
    };
    int*    cnt     = (int*)take((size_t)N * 4);
    int*    fillc   = (int*)take((size_t)N * 4);
    int*    row_ptr = (int*)take((size_t)(N + 1) * 4);
    int*    bsum    = (int*)take(1024 * 4);
    int*    col     = (int*)take((size_t)E * 4);
    float*  dinv    = (float*)take((size_t)N * 4);
    __half* bufA    = (__half*)take((size_t)N * 128 * 2);
    __half* bufB    = (__half*)take((size_t)N * 128 * 2);
    (void)ws_size;

    hipMemsetAsync(cnt, 0, (size_t)N * 4, stream);
    hipMemsetAsync(fillc, 0, (size_t)N * 4, stream);

    int gE = (E + 255) / 256;
    int gN = (N + 255) / 256;
    int nb = (N + 1023) / 1024;

    // ---- CSR build ----
    k_count<<<gE, 256, 0, stream>>>(dst, E, cnt);
    k_dinv<<<gN, 256, 0, stream>>>(cnt, dinv, N);
    k_scan1<<<nb, 256, 0, stream>>>(cnt, row_ptr, bsum, N);
    k_scan2<<<1, 128, 0, stream>>>(bsum, nb);
    k_scan3<<<(N + 1 + 255) / 256, 256, 0, stream>>>(row_ptr, bsum, N, E);
    k_fill<<<gE, 256, 0, stream>>>(src, dst, E, row_ptr, fillc, col);

    // ---- Layer 1: 128 -> 128 ----
    k_matmul_scale<128, 128, false><<<(N + 31) / 32, 256, 0, stream>>>(x, W1, dinv, bufA, N);
    k_aggregate_h<128, true><<<((size_t)N * 16 + 255) / 256, 256, 0, stream>>>(
        bufA, dinv, b1, row_ptr, col, bufB, N);

    // ---- Layer 2: 128 -> 64 ----
    k_matmul_scale<128, 64, true><<<(N + 63) / 64, 256, 0, stream>>>(bufB, W2, dinv, bufA, N);
    k_aggregate_h<64, true><<<((size_t)N * 8 + 255) / 256, 256, 0, stream>>>(
        bufA, dinv, b2, row_ptr, col, bufB, N);

    // ---- Layer 3: 64 -> 32 ----
    k_matmul_scale<64, 32, true><<<(N + 127) / 128, 256, 0, stream>>>(bufB, W3, dinv, bufA, N);
    k_aggregate_h<32, true><<<((size_t)N * 4 + 255) / 256, 256, 0, stream>>>(
        bufA, dinv, b3, row_ptr, col, bufB, N);

    // ---- Link head: [N,32] @ [32,1] + sigmoid ----
    k_final<<<gN, 256, 0, stream>>>(bufB, Wl, bl, (float*)d_out, N);
}

// Round 4
// 384.876 us; speedup vs baseline: 1.6433x; 1.3145x over previous
//
#include <hip/hip_runtime.h>
#include <hip/hip_fp16.h>
#include <math.h>

// ---------------------------------------------------------------------------
// GCN 3-layer: out = sigmoid( L3(relu(L2(relu(L1(x))))) @ Wl + bl )
// Layer: hs = half((x @ W) * dinv[row]);  z = relu(dinv[d]*(hs[d]+sum hs[s])+b)
// fp32 accumulate, fp16 storage (R3: halves gather traffic; absmax 2e-3).
// R4: CSR build via bucket partition (512 nodes/bucket) — kills the
// scattered-write WRITE_SIZE blowup (107 MB -> ~20 MB) of k_count/k_fill.
// Packing: edge = (dst&511)<<17 | src  (needs N < 2^17; here N=100000).
// ---------------------------------------------------------------------------

#define BSHIFT 9
#define BNODES (1 << BSHIFT)
#define SRCBITS 17

union H8 { float4 f4; __half2 h2[4]; };
union H4 { float2 f2; __half2 h2[2]; };

// Pass 1: bucket histogram (LDS-privatized, one global atomic/bucket/block).
__global__ __launch_bounds__(256) void k_hist(const int* __restrict__ dst, int E,
                                              int* __restrict__ bucketcnt, int B) {
    __shared__ int h[256];
    int tid = threadIdx.x;
    h[tid] = 0;
    __syncthreads();
    for (int i = blockIdx.x * 256 + tid; i < E; i += gridDim.x * 256)
        atomicAdd(&h[dst[i] >> BSHIFT], 1);
    __syncthreads();
    if (tid < B && h[tid] > 0) atomicAdd(&bucketcnt[tid], h[tid]);
}

// Pass 2: exclusive scan of bucket counts (B <= 256), one block.
__global__ __launch_bounds__(256) void k_bscan(const int* __restrict__ bucketcnt,
                                               int* __restrict__ bucketbase,
                                               int* __restrict__ bucketfill,
                                               int* __restrict__ row_ptr,
                                               int B, int n, int E) {
    __shared__ int s[256];
    int tid = threadIdx.x;
    int v = (tid < B) ? bucketcnt[tid] : 0;
    s[tid] = v;
    __syncthreads();
    for (int off = 1; off < 256; off <<= 1) {
        int t = (tid >= off) ? s[tid - off] : 0;
        __syncthreads();
        s[tid] += t;
        __syncthreads();
    }
    int excl = s[tid] - v;
    if (tid < B) { bucketbase[tid] = excl; bucketfill[tid] = excl; }
    if (tid == 0) { bucketbase[B] = E; row_ptr[n] = E; }
}

// Pass 3: partition edges into bucket streams (packed 4B/edge).
__global__ __launch_bounds__(256) void k_bucket(const int* __restrict__ src,
                                                const int* __restrict__ dst, int E,
                                                int* __restrict__ bucketfill,
                                                unsigned int* __restrict__ edgebuf,
                                                int B) {
    __shared__ int h[256];
    __shared__ int cursor[256];
    int tid = threadIdx.x;
    int base = blockIdx.x * 8192;
    int end = min(base + 8192, E);
    h[tid] = 0;
    __syncthreads();
    for (int i = base + tid; i < end; i += 256)
        atomicAdd(&h[dst[i] >> BSHIFT], 1);
    __syncthreads();
    if (tid < B) cursor[tid] = (h[tid] > 0) ? atomicAdd(&bucketfill[tid], h[tid]) : 0;
    __syncthreads();
    for (int i = base + tid; i < end; i += 256) {
        int d = dst[i];
        int b = d >> BSHIFT;
        unsigned int pk = ((unsigned int)(d & (BNODES - 1)) << SRCBITS) | (unsigned int)src[i];
        int pos = atomicAdd(&cursor[b], 1);
        edgebuf[pos] = pk;
    }
}

// Pass 4: per-bucket exact CSR: count -> LDS scan -> row_ptr/dinv -> col fill.
// All col writes land in this bucket's contiguous window (L2-merged).
__global__ __launch_bounds__(256) void k_build(const unsigned int* __restrict__ edgebuf,
                                               const int* __restrict__ bucketbase,
                                               int* __restrict__ row_ptr,
                                               float* __restrict__ dinv,
                                               int* __restrict__ col, int n) {
    __shared__ int cnt[BNODES];
    __shared__ int s[256];
    int b = blockIdx.x;
    int tid = threadIdx.x;
    int node0 = b << BSHIFT;
    int ebase = bucketbase[b], eend = bucketbase[b + 1];
    cnt[tid] = 0;
    cnt[tid + 256] = 0;
    __syncthreads();
    for (int i = ebase + tid; i < eend; i += 256)
        atomicAdd(&cnt[edgebuf[i] >> SRCBITS], 1);
    __syncthreads();
    int c0 = cnt[2 * tid], c1 = cnt[2 * tid + 1];
    int tsum = c0 + c1;
    s[tid] = tsum;
    __syncthreads();
    for (int off = 1; off < 256; off <<= 1) {
        int t = (tid >= off) ? s[tid - off] : 0;
        __syncthreads();
        s[tid] += t;
        __syncthreads();
    }
    int excl = s[tid] - tsum;
    int pA = ebase + excl, pB = ebase + excl + c0;
    int nodeA = node0 + 2 * tid, nodeB = nodeA + 1;
    // each thread only overwrites the cnt slots it alone read -> no hazard
    cnt[2 * tid] = pA;
    cnt[2 * tid + 1] = pB;
    if (nodeA < n) { row_ptr[nodeA] = pA; dinv[nodeA] = rsqrtf((float)(c0 + 1)); }
    if (nodeB < n) { row_ptr[nodeB] = pB; dinv[nodeB] = rsqrtf((float)(c1 + 1)); }
    __syncthreads();
    for (int i = ebase + tid; i < eend; i += 256) {
        unsigned int pk = edgebuf[i];
        int dl = pk >> SRCBITS;
        int sv = (int)(pk & ((1u << SRCBITS) - 1));
        int pos = atomicAdd(&cnt[dl], 1);
        col[pos] = sv;
    }
}

// hs[row] = half( (x[row] @ W) * dinv[row] ).
template <int IN, int OUT, bool XHALF>
__global__ __launch_bounds__(256) void k_matmul_scale(const void* __restrict__ xv,
                                                      const float* __restrict__ W,
                                                      const float* __restrict__ dinv,
                                                      __half* __restrict__ out, int n) {
    constexpr int CG = OUT / 4;
    constexpr int RG = 256 / CG;
    constexpr int ROWS = RG * 4;
    __shared__ float xs[ROWS][IN];

    int tid = threadIdx.x;
    int rowbase = blockIdx.x * ROWS;

    if (!XHALF) {
        constexpr int TOT4 = ROWS * IN / 4;
        const float4* x4 = (const float4*)xv;
        for (int i = tid; i < TOT4; i += 256) {
            int r = i / (IN / 4);
            int kk = i % (IN / 4);
            int row = rowbase + r;
            float4 v = make_float4(0.f, 0.f, 0.f, 0.f);
            if (row < n) v = x4[(size_t)row * (IN / 4) + kk];
            ((float4*)&xs[r][0])[kk] = v;
        }
    } else {
        constexpr int TOT8 = ROWS * IN / 8;
        const float4* x4 = (const float4*)xv;
        for (int i = tid; i < TOT8; i += 256) {
            int r = i / (IN / 8);
            int kk = i % (IN / 8);
            int row = rowbase + r;
            H8 u;
            u.f4 = make_float4(0.f, 0.f, 0.f, 0.f);
            if (row < n) u.f4 = x4[(size_t)row * (IN / 8) + kk];
#pragma unroll
            for (int q = 0; q < 4; ++q) {
                float2 f = __half22float2(u.h2[q]);
                xs[r][kk * 8 + 2 * q + 0] = f.x;
                xs[r][kk * 8 + 2 * q + 1] = f.y;
            }
        }
    }
    __syncthreads();

    int tx = tid % CG;
    int ty = tid / CG;
    const float4* W4 = (const float4*)W;
    const float4* xr0 = (const float4*)&xs[ty * 4 + 0][0];
    const float4* xr1 = (const float4*)&xs[ty * 4 + 1][0];
    const float4* xr2 = (const float4*)&xs[ty * 4 + 2][0];
    const float4* xr3 = (const float4*)&xs[ty * 4 + 3][0];

    float4 acc0 = make_float4(0, 0, 0, 0), acc1 = acc0, acc2 = acc0, acc3 = acc0;

#pragma unroll 4
    for (int kk = 0; kk < IN / 4; ++kk) {
        float4 a0 = xr0[kk], a1 = xr1[kk], a2 = xr2[kk], a3 = xr3[kk];
        float a0a[4] = {a0.x, a0.y, a0.z, a0.w};
        float a1a[4] = {a1.x, a1.y, a1.z, a1.w};
        float a2a[4] = {a2.x, a2.y, a2.z, a2.w};
        float a3a[4] = {a3.x, a3.y, a3.z, a3.w};
#pragma unroll
        for (int j = 0; j < 4; ++j) {
            float4 w = W4[(kk * 4 + j) * CG + tx];
            acc0.x += a0a[j] * w.x; acc0.y += a0a[j] * w.y; acc0.z += a0a[j] * w.z; acc0.w += a0a[j] * w.w;
            acc1.x += a1a[j] * w.x; acc1.y += a1a[j] * w.y; acc1.z += a1a[j] * w.z; acc1.w += a1a[j] * w.w;
            acc2.x += a2a[j] * w.x; acc2.y += a2a[j] * w.y; acc2.z += a2a[j] * w.z; acc2.w += a2a[j] * w.w;
            acc3.x += a3a[j] * w.x; acc3.y += a3a[j] * w.y; acc3.z += a3a[j] * w.z; acc3.w += a3a[j] * w.w;
        }
    }

    int row0 = rowbase + ty * 4;
    float2* out2 = (float2*)out;
#pragma unroll
    for (int r = 0; r < 4; ++r) {
        int row = row0 + r;
        if (row < n) {
            float dsc = dinv[row];
            float4 a = (r == 0) ? acc0 : (r == 1) ? acc1 : (r == 2) ? acc2 : acc3;
            H4 u;
            u.h2[0] = __floats2half2_rn(a.x * dsc, a.y * dsc);
            u.h2[1] = __floats2half2_rn(a.z * dsc, a.w * dsc);
            out2[(size_t)row * CG + tx] = u.f2;
        }
    }
}

// out[d][f8] = act( dinv[d]*(hs[d][f8] + sum_j hs[col[j]][f8]) + b[f8] )
template <int F, bool RELU>
__global__ __launch_bounds__(256) void k_aggregate_h(const __half* __restrict__ hs,
                                                     const float* __restrict__ dinv,
                                                     const float* __restrict__ bias,
                                                     const int* __restrict__ row_ptr,
                                                     const int* __restrict__ col,
                                                     __half* __restrict__ out, int n) {
    constexpr int LPN = F / 8;
    int t = blockIdx.x * 256 + threadIdx.x;
    int node = t / LPN;
    int fg = t % LPN;
    if (node >= n) return;

    const float4* h4 = (const float4*)hs;
    float acc[8];
    {
        H8 u;
        u.f4 = h4[(size_t)node * LPN + fg];
#pragma unroll
        for (int q = 0; q < 4; ++q) {
            float2 f = __half22float2(u.h2[q]);
            acc[2 * q + 0] = f.x;
            acc[2 * q + 1] = f.y;
        }
    }
    int beg = row_ptr[node], end = row_ptr[node + 1];
    int j = beg;
    for (; j + 3 < end; j += 4) {
        int s0 = col[j], s1 = col[j + 1], s2 = col[j + 2], s3 = col[j + 3];
        H8 u0, u1, u2, u3;
        u0.f4 = h4[(size_t)s0 * LPN + fg];
        u1.f4 = h4[(size_t)s1 * LPN + fg];
        u2.f4 = h4[(size_t)s2 * LPN + fg];
        u3.f4 = h4[(size_t)s3 * LPN + fg];
#pragma unroll
        for (int q = 0; q < 4; ++q) {
            float2 f0 = __half22float2(u0.h2[q]);
            float2 f1 = __half22float2(u1.h2[q]);
            float2 f2 = __half22float2(u2.h2[q]);
            float2 f3 = __half22float2(u3.h2[q]);
            acc[2 * q + 0] += (f0.x + f1.x) + (f2.x + f3.x);
            acc[2 * q + 1] += (f0.y + f1.y) + (f2.y + f3.y);
        }
    }
    for (; j < end; ++j) {
        H8 u;
        u.f4 = h4[(size_t)col[j] * LPN + fg];
#pragma unroll
        for (int q = 0; q < 4; ++q) {
            float2 f = __half22float2(u.h2[q]);
            acc[2 * q + 0] += f.x;
            acc[2 * q + 1] += f.y;
        }
    }
    float dsc = dinv[node];
    H8 o;
#pragma unroll
    for (int q = 0; q < 4; ++q) {
        float v0 = fmaf(acc[2 * q + 0], dsc, bias[fg * 8 + 2 * q + 0]);
        float v1 = fmaf(acc[2 * q + 1], dsc, bias[fg * 8 + 2 * q + 1]);
        if (RELU) { v0 = fmaxf(v0, 0.f); v1 = fmaxf(v1, 0.f); }
        o.h2[q] = __floats2half2_rn(v0, v1);
    }
    ((float4*)out)[(size_t)node * LPN + fg] = o.f4;
}

__global__ void k_final(const __half* __restrict__ z, const float* __restrict__ Wl,
                        const float* __restrict__ bl, float* __restrict__ out, int n) {
    int i = blockIdx.x * blockDim.x + threadIdx.x;
    if (i >= n) return;
    const float4* z4 = (const float4*)(z + (size_t)i * 32);
    float acc = bl[0];
#pragma unroll
    for (int k = 0; k < 4; ++k) {
        H8 u;
        u.f4 = z4[k];
#pragma unroll
        for (int q = 0; q < 4; ++q) {
            float2 f = __half22float2(u.h2[q]);
            acc += f.x * Wl[k * 8 + 2 * q + 0] + f.y * Wl[k * 8 + 2 * q + 1];
        }
    }
    out[i] = 1.f / (1.f + expf(-acc));
}

extern "C" void kernel_launch(void* const* d_in, const int* in_sizes, int n_in,
                              void* d_out, int out_size, void* d_ws, size_t ws_size,
                              hipStream_t stream) {
    const float* x  = (const float*)d_in[0];
    const int*   ei = (const int*)d_in[1];
    const float* W1 = (const float*)d_in[2];
    const float* b1 = (const float*)d_in[3];
    const float* W2 = (const float*)d_in[4];
    const float* b2 = (const float*)d_in[5];
    const float* W3 = (const float*)d_in[6];
    const float* b3 = (const float*)d_in[7];
    const float* Wl = (const float*)d_in[8];
    const float* bl = (const float*)d_in[9];

    const int N = in_sizes[0] / 128;
    const int E = in_sizes[1] / 2;
    const int* src = ei;
    const int* dst = ei + E;
    const int B = (N + BNODES - 1) >> BSHIFT;  // buckets (<= 256 for N <= 131072)

    char* ws = (char*)d_ws;
    size_t off = 0;
    auto take = [&](size_t bytes) -> char* {
        char* p = ws + off;
        off += (bytes + 255) & ~(size_t)255;
        return p;
    };
    int*          bucketcnt  = (int*)take(256 * 4);
    int*          bucketbase = (int*)take(257 * 4);
    int*          bucketfill = (int*)take(256 * 4);
    unsigned int* edgebuf    = (unsigned int*)take((size_t)E * 4);
    int*          row_ptr    = (int*)take((size_t)(N + 1) * 4);
    float*        dinv       = (float*)take((size_t)N * 4);
    int*          col        = (int*)take((size_t)E * 4);
    __half*       bufA       = (__half*)take((size_t)N * 128 * 2);
    __half*       bufB       = (__half*)take((size_t)N * 128 * 2);
    (void)ws_size;

    hipMemsetAsync(bucketcnt, 0, 256 * 4, stream);

    int gN = (N + 255) / 256;

    // ---- CSR build (bucketed) ----
    k_hist<<<512, 256, 0, stream>>>(dst, E, bucketcnt, B);
    k_bscan<<<1, 256, 0, stream>>>(bucketcnt, bucketbase, bucketfill, row_ptr, B, N, E);
    k_bucket<<<(E + 8191) / 8192, 256, 0, stream>>>(src, dst, E, bucketfill, edgebuf, B);
    k_build<<<B, 256, 0, stream>>>(edgebuf, bucketbase, row_ptr, dinv, col, N);

    // ---- Layer 1: 128 -> 128 ----
    k_matmul_scale<128, 128, false><<<(N + 31) / 32, 256, 0, stream>>>(x, W1, dinv, bufA, N);
    k_aggregate_h<128, true><<<((size_t)N * 16 + 255) / 256, 256, 0, stream>>>(
        bufA, dinv, b1, row_ptr, col, bufB, N);

    // ---- Layer 2: 128 -> 64 ----
    k_matmul_scale<128, 64, true><<<(N + 63) / 64, 256, 0, stream>>>(bufB, W2, dinv, bufA, N);
    k_aggregate_h<64, true><<<((size_t)N * 8 + 255) / 256, 256, 0, stream>>>(
        bufA, dinv, b2, row_ptr, col, bufB, N);

    // ---- Layer 3: 64 -> 32 ----
    k_matmul_scale<64, 32, true><<<(N + 127) / 128, 256, 0, stream>>>(bufB, W3, dinv, bufA, N);
    k_aggregate_h<32, true><<<((size_t)N * 4 + 255) / 256, 256, 0, stream>>>(
        bufA, dinv, b3, row_ptr, col, bufB, N);

    // ---- Link head: [N,32] @ [32,1] + sigmoid ----
    k_final<<<gN, 256, 0, stream>>>(bufB, Wl, bl, (float*)d_out, N);
}

// Round 5
// 319.923 us; speedup vs baseline: 1.9769x; 1.2030x over previous
//
#include <hip/hip_runtime.h>
#include <hip/hip_fp16.h>
#include <math.h>

// ---------------------------------------------------------------------------
// GCN 3-layer: out = sigmoid( L3(relu(L2(relu(L1(x))))) @ Wl + bl )
// Layer: hs = half((x @ W) * dinv[row]);  z = relu(dinv[d]*(hs[d]+sum hs[s])+b)
// fp32 accumulate, fp16 storage. CSR via bucket partition (R4).
// R5: matmuls -> v_mfma_f32_16x16x32_f16 (fp16 in, fp32 acc). W pre-packed
// into B-fragment order; A staged in LDS fp16 (pad 8 halves -> <=2-way bank).
// Layouts (m89-verified): A[m=lane&15][k=quad*8+j]; C/D col=lane&15,
// row=quad*4+reg.
// ---------------------------------------------------------------------------

#define BSHIFT 9
#define BNODES (1 << BSHIFT)
#define SRCBITS 17

union H8 { float4 f4; __half2 h2[4]; };

typedef _Float16 half8 __attribute__((ext_vector_type(8)));
typedef float floatx4 __attribute__((ext_vector_type(4)));

// ---------------- CSR build (bucketed) ----------------

__global__ __launch_bounds__(256) void k_hist(const int* __restrict__ dst, int E,
                                              int* __restrict__ bucketcnt, int B) {
    __shared__ int h[256];
    int tid = threadIdx.x;
    h[tid] = 0;
    __syncthreads();
    for (int i = blockIdx.x * 256 + tid; i < E; i += gridDim.x * 256)
        atomicAdd(&h[dst[i] >> BSHIFT], 1);
    __syncthreads();
    if (tid < B && h[tid] > 0) atomicAdd(&bucketcnt[tid], h[tid]);
}

__global__ __launch_bounds__(256) void k_bscan(const int* __restrict__ bucketcnt,
                                               int* __restrict__ bucketbase,
                                               int* __restrict__ bucketfill,
                                               int* __restrict__ row_ptr,
                                               int B, int n, int E) {
    __shared__ int s[256];
    int tid = threadIdx.x;
    int v = (tid < B) ? bucketcnt[tid] : 0;
    s[tid] = v;
    __syncthreads();
    for (int off = 1; off < 256; off <<= 1) {
        int t = (tid >= off) ? s[tid - off] : 0;
        __syncthreads();
        s[tid] += t;
        __syncthreads();
    }
    int excl = s[tid] - v;
    if (tid < B) { bucketbase[tid] = excl; bucketfill[tid] = excl; }
    if (tid == 0) { bucketbase[B] = E; row_ptr[n] = E; }
}

__global__ __launch_bounds__(256) void k_bucket(const int* __restrict__ src,
                                                const int* __restrict__ dst, int E,
                                                int* __restrict__ bucketfill,
                                                unsigned int* __restrict__ edgebuf,
                                                int B) {
    __shared__ int h[256];
    __shared__ int cursor[256];
    int tid = threadIdx.x;
    int base = blockIdx.x * 8192;
    int end = min(base + 8192, E);
    h[tid] = 0;
    __syncthreads();
    for (int i = base + tid; i < end; i += 256)
        atomicAdd(&h[dst[i] >> BSHIFT], 1);
    __syncthreads();
    if (tid < B) cursor[tid] = (h[tid] > 0) ? atomicAdd(&bucketfill[tid], h[tid]) : 0;
    __syncthreads();
    for (int i = base + tid; i < end; i += 256) {
        int d = dst[i];
        int b = d >> BSHIFT;
        unsigned int pk = ((unsigned int)(d & (BNODES - 1)) << SRCBITS) | (unsigned int)src[i];
        int pos = atomicAdd(&cursor[b], 1);
        edgebuf[pos] = pk;
    }
}

__global__ __launch_bounds__(256) void k_build(const unsigned int* __restrict__ edgebuf,
                                               const int* __restrict__ bucketbase,
                                               int* __restrict__ row_ptr,
                                               float* __restrict__ dinv,
                                               int* __restrict__ col, int n) {
    __shared__ int cnt[BNODES];
    __shared__ int s[256];
    int b = blockIdx.x;
    int tid = threadIdx.x;
    int node0 = b << BSHIFT;
    int ebase = bucketbase[b], eend = bucketbase[b + 1];
    cnt[tid] = 0;
    cnt[tid + 256] = 0;
    __syncthreads();
    for (int i = ebase + tid; i < eend; i += 256)
        atomicAdd(&cnt[edgebuf[i] >> SRCBITS], 1);
    __syncthreads();
    int c0 = cnt[2 * tid], c1 = cnt[2 * tid + 1];
    int tsum = c0 + c1;
    s[tid] = tsum;
    __syncthreads();
    for (int off = 1; off < 256; off <<= 1) {
        int t = (tid >= off) ? s[tid - off] : 0;
        __syncthreads();
        s[tid] += t;
        __syncthreads();
    }
    int excl = s[tid] - tsum;
    int pA = ebase + excl, pB = ebase + excl + c0;
    int nodeA = node0 + 2 * tid, nodeB = nodeA + 1;
    cnt[2 * tid] = pA;
    cnt[2 * tid + 1] = pB;
    if (nodeA < n) { row_ptr[nodeA] = pA; dinv[nodeA] = rsqrtf((float)(c0 + 1)); }
    if (nodeB < n) { row_ptr[nodeB] = pB; dinv[nodeB] = rsqrtf((float)(c1 + 1)); }
    __syncthreads();
    for (int i = ebase + tid; i < eend; i += 256) {
        unsigned int pk = edgebuf[i];
        int dl = pk >> SRCBITS;
        int sv = (int)(pk & ((1u << SRCBITS) - 1));
        int pos = atomicAdd(&cnt[dl], 1);
        col[pos] = sv;
    }
}

// ---------------- W pack: fp32 [IN][OUT] -> fp16 B-fragment order ----------
// frag element e: j=e&7, lane=(e>>3)&63, (s*NT+t)=e>>9
// value = W[(s*32 + (lane>>4)*8 + j)*OUT + t*16 + (lane&15)]
__global__ void k_packW(const float* __restrict__ W, _Float16* __restrict__ Wpk,
                        int IN, int OUT) {
    int e = blockIdx.x * 256 + threadIdx.x;
    if (e >= IN * OUT) return;
    int j = e & 7;
    int lane = (e >> 3) & 63;
    int rest = e >> 9;
    int NT = OUT >> 4;
    int t = rest % NT;
    int s = rest / NT;
    int k = s * 32 + (lane >> 4) * 8 + j;
    int nn = t * 16 + (lane & 15);
    Wpk[e] = (_Float16)W[k * OUT + nn];
}

// ---------------- MFMA matmul: hs = half((x@W)*dinv[row]) ------------------
template <int IN, int OUT, bool XHALF>
__global__ __launch_bounds__(256) void k_matmul_mfma(const void* __restrict__ xv,
                                                     const _Float16* __restrict__ Wpk,
                                                     const float* __restrict__ dinv,
                                                     __half* __restrict__ out, int n) {
    constexpr int S = IN / 32;        // K steps
    constexpr int NT = OUT / 16;      // column tiles
    constexpr int LDH = IN + 8;       // padded LDS row (halves)
    __shared__ _Float16 xs[64 * LDH];

    int tid = threadIdx.x;
    int rowbase = blockIdx.x * 64;

    // stage 64 rows of x into LDS as fp16 (coalesced 16B global loads)
    constexpr int TOT = 64 * IN / 8;
    const float4* x4 = (const float4*)xv;
    for (int i = tid; i < TOT; i += 256) {
        int r = i / (IN / 8), kg = i % (IN / 8);
        int row = rowbase + r;
        if (XHALF) {
            float4 v = make_float4(0.f, 0.f, 0.f, 0.f);
            if (row < n) v = x4[(size_t)row * (IN / 8) + kg];
            *(float4*)&xs[r * LDH + kg * 8] = v;
        } else {
            float4 a = make_float4(0.f, 0.f, 0.f, 0.f), b = a;
            if (row < n) {
                a = x4[(size_t)row * (IN / 4) + kg * 2 + 0];
                b = x4[(size_t)row * (IN / 4) + kg * 2 + 1];
            }
            _Float16* p = &xs[r * LDH + kg * 8];
            p[0] = (_Float16)a.x; p[1] = (_Float16)a.y;
            p[2] = (_Float16)a.z; p[3] = (_Float16)a.w;
            p[4] = (_Float16)b.x; p[5] = (_Float16)b.y;
            p[6] = (_Float16)b.z; p[7] = (_Float16)b.w;
        }
    }
    __syncthreads();

    int lane = tid & 63;
    int wave = tid >> 6;
    int m = lane & 15, quad = lane >> 4;

    floatx4 acc[NT];
#pragma unroll
    for (int t = 0; t < NT; ++t) acc[t] = (floatx4){0.f, 0.f, 0.f, 0.f};

    const half8* Wf = (const half8*)Wpk;
#pragma unroll
    for (int s = 0; s < S; ++s) {
        half8 a = *(const half8*)&xs[(wave * 16 + m) * LDH + s * 32 + quad * 8];
#pragma unroll
        for (int t = 0; t < NT; ++t) {
            half8 b = Wf[(s * NT + t) * 64 + lane];
            acc[t] = __builtin_amdgcn_mfma_f32_16x16x32_f16(a, b, acc[t], 0, 0, 0);
        }
    }

    // epilogue: C/D col=lane&15, row=quad*4+reg
    int rbase = rowbase + wave * 16 + quad * 4;
#pragma unroll
    for (int r = 0; r < 4; ++r) {
        int row = rbase + r;
        if (row < n) {
            float dsc = dinv[row];
#pragma unroll
            for (int t = 0; t < NT; ++t)
                out[(size_t)row * OUT + t * 16 + m] = __float2half(acc[t][r] * dsc);
        }
    }
}

// ---------------- aggregate: z = act(dinv[d]*(hs[d]+sum hs[s]) + b) --------
template <int F, bool RELU>
__global__ __launch_bounds__(256) void k_aggregate_h(const __half* __restrict__ hs,
                                                     const float* __restrict__ dinv,
                                                     const float* __restrict__ bias,
                                                     const int* __restrict__ row_ptr,
                                                     const int* __restrict__ col,
                                                     __half* __restrict__ out, int n) {
    constexpr int LPN = F / 8;
    int t = blockIdx.x * 256 + threadIdx.x;
    int node = t / LPN;
    int fg = t % LPN;
    if (node >= n) return;

    const float4* h4 = (const float4*)hs;
    float acc[8];
    {
        H8 u;
        u.f4 = h4[(size_t)node * LPN + fg];
#pragma unroll
        for (int q = 0; q < 4; ++q) {
            float2 f = __half22float2(u.h2[q]);
            acc[2 * q + 0] = f.x;
            acc[2 * q + 1] = f.y;
        }
    }
    int beg = row_ptr[node], end = row_ptr[node + 1];
    int j = beg;
    for (; j + 3 < end; j += 4) {
        int s0 = col[j], s1 = col[j + 1], s2 = col[j + 2], s3 = col[j + 3];
        H8 u0, u1, u2, u3;
        u0.f4 = h4[(size_t)s0 * LPN + fg];
        u1.f4 = h4[(size_t)s1 * LPN + fg];
        u2.f4 = h4[(size_t)s2 * LPN + fg];
        u3.f4 = h4[(size_t)s3 * LPN + fg];
#pragma unroll
        for (int q = 0; q < 4; ++q) {
            float2 f0 = __half22float2(u0.h2[q]);
            float2 f1 = __half22float2(u1.h2[q]);
            float2 f2 = __half22float2(u2.h2[q]);
            float2 f3 = __half22float2(u3.h2[q]);
            acc[2 * q + 0] += (f0.x + f1.x) + (f2.x + f3.x);
            acc[2 * q + 1] += (f0.y + f1.y) + (f2.y + f3.y);
        }
    }
    for (; j < end; ++j) {
        H8 u;
        u.f4 = h4[(size_t)col[j] * LPN + fg];
#pragma unroll
        for (int q = 0; q < 4; ++q) {
            float2 f = __half22float2(u.h2[q]);
            acc[2 * q + 0] += f.x;
            acc[2 * q + 1] += f.y;
        }
    }
    float dsc = dinv[node];
    H8 o;
#pragma unroll
    for (int q = 0; q < 4; ++q) {
        float v0 = fmaf(acc[2 * q + 0], dsc, bias[fg * 8 + 2 * q + 0]);
        float v1 = fmaf(acc[2 * q + 1], dsc, bias[fg * 8 + 2 * q + 1]);
        if (RELU) { v0 = fmaxf(v0, 0.f); v1 = fmaxf(v1, 0.f); }
        o.h2[q] = __floats2half2_rn(v0, v1);
    }
    ((float4*)out)[(size_t)node * LPN + fg] = o.f4;
}

__global__ void k_final(const __half* __restrict__ z, const float* __restrict__ Wl,
                        const float* __restrict__ bl, float* __restrict__ out, int n) {
    int i = blockIdx.x * blockDim.x + threadIdx.x;
    if (i >= n) return;
    const float4* z4 = (const float4*)(z + (size_t)i * 32);
    float acc = bl[0];
#pragma unroll
    for (int k = 0; k < 4; ++k) {
        H8 u;
        u.f4 = z4[k];
#pragma unroll
        for (int q = 0; q < 4; ++q) {
            float2 f = __half22float2(u.h2[q]);
            acc += f.x * Wl[k * 8 + 2 * q + 0] + f.y * Wl[k * 8 + 2 * q + 1];
        }
    }
    out[i] = 1.f / (1.f + expf(-acc));
}

extern "C" void kernel_launch(void* const* d_in, const int* in_sizes, int n_in,
                              void* d_out, int out_size, void* d_ws, size_t ws_size,
                              hipStream_t stream) {
    const float* x  = (const float*)d_in[0];
    const int*   ei = (const int*)d_in[1];
    const float* W1 = (const float*)d_in[2];
    const float* b1 = (const float*)d_in[3];
    const float* W2 = (const float*)d_in[4];
    const float* b2 = (const float*)d_in[5];
    const float* W3 = (const float*)d_in[6];
    const float* b3 = (const float*)d_in[7];
    const float* Wl = (const float*)d_in[8];
    const float* bl = (const float*)d_in[9];

    const int N = in_sizes[0] / 128;
    const int E = in_sizes[1] / 2;
    const int* src = ei;
    const int* dst = ei + E;
    const int B = (N + BNODES - 1) >> BSHIFT;

    char* ws = (char*)d_ws;
    size_t off = 0;
    auto take = [&](size_t bytes) -> char* {
        char* p = ws + off;
        off += (bytes + 255) & ~(size_t)255;
        return p;
    };
    int*          bucketcnt  = (int*)take(256 * 4);
    int*          bucketbase = (int*)take(257 * 4);
    int*          bucketfill = (int*)take(256 * 4);
    unsigned int* edgebuf    = (unsigned int*)take((size_t)E * 4);
    int*          row_ptr    = (int*)take((size_t)(N + 1) * 4);
    float*        dinv       = (float*)take((size_t)N * 4);
    int*          col        = (int*)take((size_t)E * 4);
    __half*       bufA       = (__half*)take((size_t)N * 128 * 2);
    __half*       bufB       = (__half*)take((size_t)N * 128 * 2);
    _Float16*     Wpk1       = (_Float16*)take(128 * 128 * 2);
    _Float16*     Wpk2       = (_Float16*)take(128 * 64 * 2);
    _Float16*     Wpk3       = (_Float16*)take(64 * 32 * 2);
    (void)ws_size;

    hipMemsetAsync(bucketcnt, 0, 256 * 4, stream);

    int gN = (N + 255) / 256;
    int gM = (N + 63) / 64;

    // ---- CSR build (bucketed) ----
    k_hist<<<512, 256, 0, stream>>>(dst, E, bucketcnt, B);
    k_bscan<<<1, 256, 0, stream>>>(bucketcnt, bucketbase, bucketfill, row_ptr, B, N, E);
    k_bucket<<<(E + 8191) / 8192, 256, 0, stream>>>(src, dst, E, bucketfill, edgebuf, B);
    k_build<<<B, 256, 0, stream>>>(edgebuf, bucketbase, row_ptr, dinv, col, N);

    // ---- pack weights to fp16 B-fragment order ----
    k_packW<<<(128 * 128 + 255) / 256, 256, 0, stream>>>(W1, Wpk1, 128, 128);
    k_packW<<<(128 * 64 + 255) / 256, 256, 0, stream>>>(W2, Wpk2, 128, 64);
    k_packW<<<(64 * 32 + 255) / 256, 256, 0, stream>>>(W3, Wpk3, 64, 32);

    // ---- Layer 1: 128 -> 128 ----
    k_matmul_mfma<128, 128, false><<<gM, 256, 0, stream>>>(x, Wpk1, dinv, bufA, N);
    k_aggregate_h<128, true><<<((size_t)N * 16 + 255) / 256, 256, 0, stream>>>(
        bufA, dinv, b1, row_ptr, col, bufB, N);

    // ---- Layer 2: 128 -> 64 ----
    k_matmul_mfma<128, 64, true><<<gM, 256, 0, stream>>>(bufB, Wpk2, dinv, bufA, N);
    k_aggregate_h<64, true><<<((size_t)N * 8 + 255) / 256, 256, 0, stream>>>(
        bufA, dinv, b2, row_ptr, col, bufB, N);

    // ---- Layer 3: 64 -> 32 ----
    k_matmul_mfma<64, 32, true><<<gM, 256, 0, stream>>>(bufB, Wpk3, dinv, bufA, N);
    k_aggregate_h<32, true><<<((size_t)N * 4 + 255) / 256, 256, 0, stream>>>(
        bufA, dinv, b3, row_ptr, col, bufB, N);

    // ---- Link head: [N,32] @ [32,1] + sigmoid ----
    k_final<<<gN, 256, 0, stream>>>(bufB, Wl, bl, (float*)d_out, N);
}

// Round 6
// 294.972 us; speedup vs baseline: 2.1441x; 1.0846x over previous
//
#include <hip/hip_runtime.h>
#include <hip/hip_fp16.h>
#include <math.h>

// ---------------------------------------------------------------------------
// GCN 3-layer: out = sigmoid( L3(relu(L2(relu(L1(x))))) @ Wl + bl )
// hs = half((x @ W) * dinv[row]);  z = relu(dinv[d]*(hs[d]+sum hs[s])+b)
// fp32 accumulate, fp16 storage. CSR via bucket partition.
// R6: fused [aggregate -> MFMA matmul] kernels (z stays in LDS), final head
// fused into layer-3 aggregate (4-lane shuffle dot), CSR build parallelism
// (256-node buckets, 4096-edge partition chunks), single packW kernel.
// Aggregate FETCH floor = 8 XCDs x table bytes (R5 finding) — already there.
// ---------------------------------------------------------------------------

#define BSHIFT 8
#define BNODES (1 << BSHIFT)
#define SRCBITS 17
#define MAXB 512

union H8 { float4 f4; __half2 h2[4]; };

typedef _Float16 half8 __attribute__((ext_vector_type(8)));
typedef float floatx4 __attribute__((ext_vector_type(4)));

// ---------------- CSR build (bucketed, 256 nodes/bucket) ----------------

__global__ __launch_bounds__(256) void k_hist(const int* __restrict__ dst, int E,
                                              int* __restrict__ bucketcnt, int B) {
    __shared__ int h[MAXB];
    int tid = threadIdx.x;
    h[tid] = 0; h[tid + 256] = 0;
    __syncthreads();
    for (int i = blockIdx.x * 256 + tid; i < E; i += gridDim.x * 256)
        atomicAdd(&h[dst[i] >> BSHIFT], 1);
    __syncthreads();
    if (tid < B && h[tid] > 0) atomicAdd(&bucketcnt[tid], h[tid]);
    int t2 = tid + 256;
    if (t2 < B && h[t2] > 0) atomicAdd(&bucketcnt[t2], h[t2]);
}

__global__ __launch_bounds__(512) void k_bscan(const int* __restrict__ bucketcnt,
                                               int* __restrict__ bucketbase,
                                               int* __restrict__ bucketfill,
                                               int* __restrict__ row_ptr,
                                               int B, int n, int E) {
    __shared__ int s[MAXB];
    int tid = threadIdx.x;
    int v = (tid < B) ? bucketcnt[tid] : 0;
    s[tid] = v;
    __syncthreads();
    for (int off = 1; off < MAXB; off <<= 1) {
        int t = (tid >= off) ? s[tid - off] : 0;
        __syncthreads();
        s[tid] += t;
        __syncthreads();
    }
    int excl = s[tid] - v;
    if (tid < B) { bucketbase[tid] = excl; bucketfill[tid] = excl; }
    if (tid == 0) { bucketbase[B] = E; row_ptr[n] = E; }
}

__global__ __launch_bounds__(256) void k_bucket(const int* __restrict__ src,
                                                const int* __restrict__ dst, int E,
                                                int* __restrict__ bucketfill,
                                                unsigned int* __restrict__ edgebuf,
                                                int B) {
    __shared__ int h[MAXB];
    __shared__ int cursor[MAXB];
    int tid = threadIdx.x;
    int base = blockIdx.x * 4096;
    int end = min(base + 4096, E);
    h[tid] = 0; h[tid + 256] = 0;
    __syncthreads();
    for (int i = base + tid; i < end; i += 256)
        atomicAdd(&h[dst[i] >> BSHIFT], 1);
    __syncthreads();
    if (tid < B) cursor[tid] = (h[tid] > 0) ? atomicAdd(&bucketfill[tid], h[tid]) : 0;
    int t2 = tid + 256;
    if (t2 < B) cursor[t2] = (h[t2] > 0) ? atomicAdd(&bucketfill[t2], h[t2]) : 0;
    __syncthreads();
    for (int i = base + tid; i < end; i += 256) {
        int d = dst[i];
        int b = d >> BSHIFT;
        unsigned int pk = ((unsigned int)(d & (BNODES - 1)) << SRCBITS) | (unsigned int)src[i];
        int pos = atomicAdd(&cursor[b], 1);
        edgebuf[pos] = pk;
    }
}

__global__ __launch_bounds__(256) void k_build(const unsigned int* __restrict__ edgebuf,
                                               const int* __restrict__ bucketbase,
                                               int* __restrict__ row_ptr,
                                               float* __restrict__ dinv,
                                               int* __restrict__ col, int n) {
    __shared__ int cnt[BNODES];
    __shared__ int s[BNODES];
    int b = blockIdx.x;
    int tid = threadIdx.x;
    int node0 = b << BSHIFT;
    int ebase = bucketbase[b], eend = bucketbase[b + 1];
    cnt[tid] = 0;
    __syncthreads();
    for (int i = ebase + tid; i < eend; i += 256)
        atomicAdd(&cnt[edgebuf[i] >> SRCBITS], 1);
    __syncthreads();
    int c = cnt[tid];
    s[tid] = c;
    __syncthreads();
    for (int off = 1; off < 256; off <<= 1) {
        int t = (tid >= off) ? s[tid - off] : 0;
        __syncthreads();
        s[tid] += t;
        __syncthreads();
    }
    int p = ebase + s[tid] - c;
    int node = node0 + tid;
    if (node < n) { row_ptr[node] = p; dinv[node] = rsqrtf((float)(c + 1)); }
    cnt[tid] = p;
    __syncthreads();
    for (int i = ebase + tid; i < eend; i += 256) {
        unsigned int pk = edgebuf[i];
        int pos = atomicAdd(&cnt[pk >> SRCBITS], 1);
        col[pos] = (int)(pk & ((1u << SRCBITS) - 1));
    }
}

// ---------------- W pack (all three) into fp16 B-fragment order ----------
__global__ void k_packW3(const float* __restrict__ W1, const float* __restrict__ W2,
                         const float* __restrict__ W3, _Float16* __restrict__ P1,
                         _Float16* __restrict__ P2, _Float16* __restrict__ P3) {
    int e = blockIdx.x * 256 + threadIdx.x;
    const float* W; _Float16* P; int OUT, idx;
    if (e < 16384)      { W = W1; P = P1; OUT = 128; idx = e; }
    else if (e < 24576) { W = W2; P = P2; OUT = 64;  idx = e - 16384; }
    else if (e < 26624) { W = W3; P = P3; OUT = 32;  idx = e - 24576; }
    else return;
    int j = idx & 7;
    int lane = (idx >> 3) & 63;
    int rest = idx >> 9;
    int NT = OUT >> 4;
    int t = rest % NT;
    int ss = rest / NT;
    int k = ss * 32 + (lane >> 4) * 8 + j;
    int nn = t * 16 + (lane & 15);
    P[idx] = (_Float16)W[k * OUT + nn];
}

// ---------------- MFMA matmul (layer 1): hs = half((x@W)*dinv[row]) -------
template <int IN, int OUT>
__global__ __launch_bounds__(256) void k_matmul_mfma(const float* __restrict__ x,
                                                     const _Float16* __restrict__ Wpk,
                                                     const float* __restrict__ dinv,
                                                     __half* __restrict__ out, int n) {
    constexpr int S = IN / 32;
    constexpr int NT = OUT / 16;
    constexpr int LDH = IN + 8;
    __shared__ _Float16 xs[64 * LDH];

    int tid = threadIdx.x;
    int rowbase = blockIdx.x * 64;

    constexpr int TOT = 64 * IN / 8;
    const float4* x4 = (const float4*)x;
    for (int i = tid; i < TOT; i += 256) {
        int r = i / (IN / 8), kg = i % (IN / 8);
        int row = rowbase + r;
        float4 a = make_float4(0.f, 0.f, 0.f, 0.f), b = a;
        if (row < n) {
            a = x4[(size_t)row * (IN / 4) + kg * 2 + 0];
            b = x4[(size_t)row * (IN / 4) + kg * 2 + 1];
        }
        _Float16* p = &xs[r * LDH + kg * 8];
        p[0] = (_Float16)a.x; p[1] = (_Float16)a.y;
        p[2] = (_Float16)a.z; p[3] = (_Float16)a.w;
        p[4] = (_Float16)b.x; p[5] = (_Float16)b.y;
        p[6] = (_Float16)b.z; p[7] = (_Float16)b.w;
    }
    __syncthreads();

    int lane = tid & 63;
    int wave = tid >> 6;
    int m = lane & 15, quad = lane >> 4;

    floatx4 acc[NT];
#pragma unroll
    for (int t = 0; t < NT; ++t) acc[t] = (floatx4){0.f, 0.f, 0.f, 0.f};

    const half8* Wf = (const half8*)Wpk;
#pragma unroll
    for (int s = 0; s < S; ++s) {
        half8 a = *(const half8*)&xs[(wave * 16 + m) * LDH + s * 32 + quad * 8];
#pragma unroll
        for (int t = 0; t < NT; ++t) {
            half8 b = Wf[(s * NT + t) * 64 + lane];
            acc[t] = __builtin_amdgcn_mfma_f32_16x16x32_f16(a, b, acc[t], 0, 0, 0);
        }
    }

    int rbase = rowbase + wave * 16 + quad * 4;
#pragma unroll
    for (int r = 0; r < 4; ++r) {
        int row = rbase + r;
        if (row < n) {
            float dsc = dinv[row];
#pragma unroll
            for (int t = 0; t < NT; ++t)
                out[(size_t)row * OUT + t * 16 + m] = __float2half(acc[t][r] * dsc);
        }
    }
}

// ------- fused: z = relu(dinv*(agg hs)+b) in LDS, then hs' = (z@W)*dinv ----
// F: aggregated feature width (input); OUT: matmul output width.
template <int F, int OUT>
__global__ __launch_bounds__(256) void k_agg_mm(const __half* __restrict__ hs,
                                                const float* __restrict__ dinv,
                                                const float* __restrict__ bias,
                                                const int* __restrict__ row_ptr,
                                                const int* __restrict__ col,
                                                const _Float16* __restrict__ Wpk,
                                                __half* __restrict__ out, int n) {
    constexpr int S = F / 32;
    constexpr int NT = OUT / 16;
    constexpr int LDH = F + 8;
    constexpr int LPN = F / 8;
    __shared__ _Float16 zs[64 * LDH];

    int tid = threadIdx.x;
    int rowbase = blockIdx.x * 64;
    const float4* h4 = (const float4*)hs;

    // ---- aggregate 64 dst rows into LDS (fp32 acc, fp16 store) ----
    for (int task = tid; task < 64 * LPN; task += 256) {
        int nl = task / LPN;
        int fg = task % LPN;
        int node = rowbase + nl;
        H8 o;
        if (node < n) {
            float acc[8];
            H8 u;
            u.f4 = h4[(size_t)node * LPN + fg];  // self loop
#pragma unroll
            for (int q = 0; q < 4; ++q) {
                float2 f = __half22float2(u.h2[q]);
                acc[2 * q + 0] = f.x;
                acc[2 * q + 1] = f.y;
            }
            int beg = row_ptr[node], end = row_ptr[node + 1];
            int j = beg;
            for (; j + 3 < end; j += 4) {
                int s0 = col[j], s1 = col[j + 1], s2 = col[j + 2], s3 = col[j + 3];
                H8 u0, u1, u2, u3;
                u0.f4 = h4[(size_t)s0 * LPN + fg];
                u1.f4 = h4[(size_t)s1 * LPN + fg];
                u2.f4 = h4[(size_t)s2 * LPN + fg];
                u3.f4 = h4[(size_t)s3 * LPN + fg];
#pragma unroll
                for (int q = 0; q < 4; ++q) {
                    float2 f0 = __half22float2(u0.h2[q]);
                    float2 f1 = __half22float2(u1.h2[q]);
                    float2 f2 = __half22float2(u2.h2[q]);
                    float2 f3 = __half22float2(u3.h2[q]);
                    acc[2 * q + 0] += (f0.x + f1.x) + (f2.x + f3.x);
                    acc[2 * q + 1] += (f0.y + f1.y) + (f2.y + f3.y);
                }
            }
            for (; j < end; ++j) {
                H8 u2;
                u2.f4 = h4[(size_t)col[j] * LPN + fg];
#pragma unroll
                for (int q = 0; q < 4; ++q) {
                    float2 f = __half22float2(u2.h2[q]);
                    acc[2 * q + 0] += f.x;
                    acc[2 * q + 1] += f.y;
                }
            }
            float dsc = dinv[node];
#pragma unroll
            for (int q = 0; q < 4; ++q) {
                float v0 = fmaxf(fmaf(acc[2 * q + 0], dsc, bias[fg * 8 + 2 * q + 0]), 0.f);
                float v1 = fmaxf(fmaf(acc[2 * q + 1], dsc, bias[fg * 8 + 2 * q + 1]), 0.f);
                o.h2[q] = __floats2half2_rn(v0, v1);
            }
        } else {
            o.f4 = make_float4(0.f, 0.f, 0.f, 0.f);
        }
        *(float4*)&zs[nl * LDH + fg * 8] = o.f4;
    }
    __syncthreads();

    // ---- MFMA: hs' = half((z @ W) * dinv[row]) ----
    int lane = tid & 63;
    int wave = tid >> 6;
    int m = lane & 15, quad = lane >> 4;

    floatx4 acc[NT];
#pragma unroll
    for (int t = 0; t < NT; ++t) acc[t] = (floatx4){0.f, 0.f, 0.f, 0.f};

    const half8* Wf = (const half8*)Wpk;
#pragma unroll
    for (int s = 0; s < S; ++s) {
        half8 a = *(const half8*)&zs[(wave * 16 + m) * LDH + s * 32 + quad * 8];
#pragma unroll
        for (int t = 0; t < NT; ++t) {
            half8 b = Wf[(s * NT + t) * 64 + lane];
            acc[t] = __builtin_amdgcn_mfma_f32_16x16x32_f16(a, b, acc[t], 0, 0, 0);
        }
    }

    int rbase = rowbase + wave * 16 + quad * 4;
#pragma unroll
    for (int r = 0; r < 4; ++r) {
        int row = rbase + r;
        if (row < n) {
            float dsc = dinv[row];
#pragma unroll
            for (int t = 0; t < NT; ++t)
                out[(size_t)row * OUT + t * 16 + m] = __float2half(acc[t][r] * dsc);
        }
    }
}

// ------- fused layer-3 aggregate + link head (F=32) ------------------------
// z = relu(dinv*(agg hs)+b); out = sigmoid(z . Wl + bl), 4 lanes/node.
__global__ __launch_bounds__(256) void k_agg_final(const __half* __restrict__ hs,
                                                   const float* __restrict__ dinv,
                                                   const float* __restrict__ bias,
                                                   const int* __restrict__ row_ptr,
                                                   const int* __restrict__ col,
                                                   const float* __restrict__ Wl,
                                                   const float* __restrict__ bl,
                                                   float* __restrict__ out, int n) {
    constexpr int LPN = 4;  // 32 feats / 8
    int t = blockIdx.x * 256 + threadIdx.x;
    int node = t / LPN;
    int fg = t % LPN;
    if (node >= n) return;

    const float4* h4 = (const float4*)hs;
    float acc[8];
    {
        H8 u;
        u.f4 = h4[(size_t)node * LPN + fg];
#pragma unroll
        for (int q = 0; q < 4; ++q) {
            float2 f = __half22float2(u.h2[q]);
            acc[2 * q + 0] = f.x;
            acc[2 * q + 1] = f.y;
        }
    }
    int beg = row_ptr[node], end = row_ptr[node + 1];
    int j = beg;
    for (; j + 3 < end; j += 4) {
        int s0 = col[j], s1 = col[j + 1], s2 = col[j + 2], s3 = col[j + 3];
        H8 u0, u1, u2, u3;
        u0.f4 = h4[(size_t)s0 * LPN + fg];
        u1.f4 = h4[(size_t)s1 * LPN + fg];
        u2.f4 = h4[(size_t)s2 * LPN + fg];
        u3.f4 = h4[(size_t)s3 * LPN + fg];
#pragma unroll
        for (int q = 0; q < 4; ++q) {
            float2 f0 = __half22float2(u0.h2[q]);
            float2 f1 = __half22float2(u1.h2[q]);
            float2 f2 = __half22float2(u2.h2[q]);
            float2 f3 = __half22float2(u3.h2[q]);
            acc[2 * q + 0] += (f0.x + f1.x) + (f2.x + f3.x);
            acc[2 * q + 1] += (f0.y + f1.y) + (f2.y + f3.y);
        }
    }
    for (; j < end; ++j) {
        H8 u;
        u.f4 = h4[(size_t)col[j] * LPN + fg];
#pragma unroll
        for (int q = 0; q < 4; ++q) {
            float2 f = __half22float2(u.h2[q]);
            acc[2 * q + 0] += f.x;
            acc[2 * q + 1] += f.y;
        }
    }
    float dsc = dinv[node];
    float partial = 0.f;
#pragma unroll
    for (int k = 0; k < 8; ++k) {
        float v = fmaxf(fmaf(acc[k], dsc, bias[fg * 8 + k]), 0.f);
        partial = fmaf(v, Wl[fg * 8 + k], partial);
    }
    partial += __shfl_xor(partial, 1);
    partial += __shfl_xor(partial, 2);
    if (fg == 0) out[node] = 1.f / (1.f + expf(-(partial + bl[0])));
}

extern "C" void kernel_launch(void* const* d_in, const int* in_sizes, int n_in,
                              void* d_out, int out_size, void* d_ws, size_t ws_size,
                              hipStream_t stream) {
    const float* x  = (const float*)d_in[0];
    const int*   ei = (const int*)d_in[1];
    const float* W1 = (const float*)d_in[2];
    const float* b1 = (const float*)d_in[3];
    const float* W2 = (const float*)d_in[4];
    const float* b2 = (const float*)d_in[5];
    const float* W3 = (const float*)d_in[6];
    const float* b3 = (const float*)d_in[7];
    const float* Wl = (const float*)d_in[8];
    const float* bl = (const float*)d_in[9];

    const int N = in_sizes[0] / 128;
    const int E = in_sizes[1] / 2;
    const int* src = ei;
    const int* dst = ei + E;
    const int B = (N + BNODES - 1) >> BSHIFT;  // <= 512 for N <= 131072

    char* ws = (char*)d_ws;
    size_t off = 0;
    auto take = [&](size_t bytes) -> char* {
        char* p = ws + off;
        off += (bytes + 255) & ~(size_t)255;
        return p;
    };
    int*          bucketcnt  = (int*)take(MAXB * 4);
    int*          bucketbase = (int*)take((MAXB + 1) * 4);
    int*          bucketfill = (int*)take(MAXB * 4);
    unsigned int* edgebuf    = (unsigned int*)take((size_t)E * 4);
    int*          row_ptr    = (int*)take((size_t)(N + 1) * 4);
    float*        dinv       = (float*)take((size_t)N * 4);
    int*          col        = (int*)take((size_t)E * 4);
    __half*       bufA       = (__half*)take((size_t)N * 128 * 2);
    __half*       bufB       = (__half*)take((size_t)N * 128 * 2);
    _Float16*     Wpk1       = (_Float16*)take(128 * 128 * 2);
    _Float16*     Wpk2       = (_Float16*)take(128 * 64 * 2);
    _Float16*     Wpk3       = (_Float16*)take(64 * 32 * 2);
    (void)ws_size;

    hipMemsetAsync(bucketcnt, 0, MAXB * 4, stream);

    int gM = (N + 63) / 64;

    // ---- CSR build (bucketed) ----
    k_hist<<<512, 256, 0, stream>>>(dst, E, bucketcnt, B);
    k_bscan<<<1, MAXB, 0, stream>>>(bucketcnt, bucketbase, bucketfill, row_ptr, B, N, E);
    k_bucket<<<(E + 4095) / 4096, 256, 0, stream>>>(src, dst, E, bucketfill, edgebuf, B);
    k_build<<<B, 256, 0, stream>>>(edgebuf, bucketbase, row_ptr, dinv, col, N);

    // ---- pack weights ----
    k_packW3<<<(26624 + 255) / 256, 256, 0, stream>>>(W1, W2, W3, Wpk1, Wpk2, Wpk3);

    // ---- Layer 1 matmul: x (fp32) -> hs1 (bufA, F=128) ----
    k_matmul_mfma<128, 128><<<gM, 256, 0, stream>>>(x, Wpk1, dinv, bufA, N);

    // ---- agg1 (F=128) + mm2 (128->64): bufA -> hs2 (bufB) ----
    k_agg_mm<128, 64><<<gM, 256, 0, stream>>>(bufA, dinv, b1, row_ptr, col, Wpk2, bufB, N);

    // ---- agg2 (F=64) + mm3 (64->32): bufB -> hs3 (bufA) ----
    k_agg_mm<64, 32><<<gM, 256, 0, stream>>>(bufB, dinv, b2, row_ptr, col, Wpk3, bufA, N);

    // ---- agg3 (F=32) + link head -> out ----
    k_agg_final<<<((size_t)N * 4 + 255) / 256, 256, 0, stream>>>(
        bufA, dinv, b3, row_ptr, col, Wl, bl, (float*)d_out, N);
}